// Round 2
// baseline (141.421 us; speedup 1.0000x reference)
//
#include <hip/hip_runtime.h>

// VectorQuantizer gather: out[b][d][n] = embedding[indices[b][n]][d]
// B=32, N=4096 (64x64), K=1024, D=256. fp32 out = 128 MiB -> write-BW bound.
//
// v3 design (write-contiguity re-tile):
//  v1 (scattered reads) and v2 (line-exact reads) both ran ~59-61 us ->
//  the shared bottleneck is the WRITE stream: 256B chunks at 16KB stride
//  gave only ~2.3 TB/s effective write BW (DRAM activate-rate bound;
//  also 16KB stride maps to only 16 of 2048 L2 sets).
//  Now:
//   - Block = (b, 32-d chunk, 1024-n tile); grid 32*8*4 = 1024 = 4/CU.
//   - Each (block, d) writes a 4 KB CONTIGUOUS run (16x larger chunks);
//     block output = 32 x 4KB in a 128 KB span -> DRAM-row friendly.
//   - Reads: block needs embedding[row][dc*32 .. +32] = one full 128 B
//     line per indexed row, 8 rows per wave-load, lines 100% consumed.
//   - Transpose via PER-WAVE private LDS tiles [32n][34] (pad -> ~2-way
//     banks = free): no __syncthreads in the main loop, no vmcnt drains;
//     same-wave LDS ordering is automatic.
//   - Register double-buffer: next sub-tile's 4 gather-float4s issued
//     before current tile's LDS/store phase (latency hidden).
//  LDS: 4KB idx + 4 waves * 32*34*4 B = 21.4 KB -> 4 blocks/CU.

#define VQ_B 32
#define VQ_N 4096
#define VQ_D 256
#define DC 32            // d-chunk per block
#define NT 1024          // n-tile per block
#define NW 256           // n per wave
#define NSUB 32          // n per sub-iteration
#define TSTRIDE 34       // LDS tile row stride in floats (pad vs 32)

__global__ __launch_bounds__(256, 4) void vq_gather_kernel(
    const int* __restrict__ indices,
    const float* __restrict__ embedding,
    float* __restrict__ out)
{
    __shared__ int   s_idx[NT];
    __shared__ float s_tile[4][NSUB * TSTRIDE];   // per-wave transpose tile

    const int bid = blockIdx.x;
    const int nt  = bid & 3;          // n-tile 0..3
    const int dc  = (bid >> 2) & 7;   // d-chunk 0..7
    const int b   = bid >> 5;         // batch 0..31

    const int t = threadIdx.x;
    const int w = t >> 6;             // wave 0..3
    const int l = t & 63;

    // stage this block's 1024 indices (coalesced, one barrier total)
    #pragma unroll
    for (int k = 0; k < 4; ++k)
        s_idx[t + 256 * k] = indices[b * VQ_N + nt * NT + t + 256 * k];
    __syncthreads();

    // load-phase mapping: 8 lanes cover one 128 B row slice
    const int s  = l & 7;             // float4 slot within row slice
    const int nn = l >> 3;            // row-in-group 0..7
    // store-phase mapping: 8 lanes cover 32 n for one d
    const int ss = l & 7;             // n-quad 0..7
    const int dd = l >> 3;            // d-in-group 0..7

    float* tile = s_tile[w];
    const float* emb_c = embedding + dc * DC;     // column offset into rows
    const int wbase = w * NW;

    // wave's output base: rows (b*256 + dc*32 + d), cols nt*1024 + w*256 + ...
    float* out_w = out + (b * VQ_D + dc * DC) * VQ_N + nt * NT + wbase;

    float4 v[4], vn[4];

    // prologue: gather sub-tile 0 (4 x float4 per lane = 32 rows x 128 B)
    #pragma unroll
    for (int k = 0; k < 4; ++k) {
        const int row = s_idx[wbase + nn + 8 * k];
        v[k] = ((const float4*)(emb_c + row * VQ_D))[s];
    }

    for (int si = 0; si < 8; ++si) {
        // prefetch next sub-tile's gathers (hide L2 latency under LDS+stores)
        if (si < 7) {
            #pragma unroll
            for (int k = 0; k < 4; ++k) {
                const int row = s_idx[wbase + (si + 1) * NSUB + nn + 8 * k];
                vn[k] = ((const float4*)(emb_c + row * VQ_D))[s];
            }
        }

        // transpose in: tile[n][d]  (scalar writes, ~2-way banks = free)
        #pragma unroll
        for (int k = 0; k < 4; ++k) {
            float* p = &tile[(nn + 8 * k) * TSTRIDE + 4 * s];
            p[0] = v[k].x; p[1] = v[k].y; p[2] = v[k].z; p[3] = v[k].w;
        }

        // transpose out: column reads -> float4 stores, 4 KB contiguous per d
        #pragma unroll
        for (int q = 0; q < 4; ++q) {
            const int d = dd + 8 * q;
            float4 o;
            o.x = tile[(4 * ss + 0) * TSTRIDE + d];
            o.y = tile[(4 * ss + 1) * TSTRIDE + d];
            o.z = tile[(4 * ss + 2) * TSTRIDE + d];
            o.w = tile[(4 * ss + 3) * TSTRIDE + d];
            *(float4*)(out_w + d * VQ_N + si * NSUB + 4 * ss) = o;
        }

        #pragma unroll
        for (int k = 0; k < 4; ++k) v[k] = vn[k];
    }
}

extern "C" void kernel_launch(void* const* d_in, const int* in_sizes, int n_in,
                              void* d_out, int out_size, void* d_ws, size_t ws_size,
                              hipStream_t stream) {
    const int*   indices   = (const int*)d_in[0];    // (32,1,4096) int32
    const float* embedding = (const float*)d_in[1];  // (1024,256) fp32
    float* out = (float*)d_out;                      // (32,256,64,64) fp32

    vq_gather_kernel<<<dim3(VQ_B * 8 * 4), dim3(256), 0, stream>>>(
        indices, embedding, out);
}